// Round 16
// baseline (266.815 us; speedup 1.0000x reference)
//
#include <hip/hip_runtime.h>
#include <math.h>
#include <stdint.h>

#define B 8
#define N 4096
#define C 64
#define D 64
#define K 16

typedef __attribute__((ext_vector_type(8))) short short8;
typedef __attribute__((ext_vector_type(4))) float f32x4;

// ---------------------------------------------------------------------------
// bf16 helpers
// ---------------------------------------------------------------------------
__device__ __forceinline__ unsigned short f2bf(float x) {
    unsigned u = __float_as_uint(x);
    unsigned r = (u + 0x7FFFu + ((u >> 16) & 1u)) >> 16;   // RNE
    return (unsigned short)r;
}
__device__ __forceinline__ float bf2f(unsigned short h) {
    return __uint_as_float(((unsigned)h) << 16);
}

// key = (d2bits<<32)|idx reinterpreted as double. d2 finite >=0 -> positive
// finite double -> IEEE ordering == integer ordering (exact tie-break kept).
// f64 fmin/fmax comparators measured FASTER than u64 cmp+cndmask (round 12).
__device__ __forceinline__ double pack_key(float d2, unsigned idx) {
    uint2 u; u.x = idx; u.y = __float_as_uint(d2);
    return __builtin_bit_cast(double, u);
}

// ---------------------------------------------------------------------------
// Kernel 0: per-row sqnorm (round-1 arithmetic, passed) + 3-term bf16 split
// ---------------------------------------------------------------------------
__global__ __launch_bounds__(256)
void prep_kernel(const float* __restrict__ F, float* __restrict__ sq,
                 unsigned short* __restrict__ HP, unsigned short* __restrict__ MP,
                 unsigned short* __restrict__ LP) {
    const int row = blockIdx.x * 256 + threadIdx.x;
    const float4* src = (const float4*)(F + (size_t)row * C);
    float4 v[16];
    #pragma unroll
    for (int q = 0; q < 16; q++) v[q] = src[q];

    {
        float r[8];
        #pragma unroll
        for (int j = 0; j < 8; j++) {
            float t = ((const float*)v)[j];
            r[j] = t * t;
        }
        #pragma unroll
        for (int m = 1; m < 8; m++) {
            #pragma unroll
            for (int j = 0; j < 8; j++) {
                float t = ((const float*)v)[8 * m + j];
                r[j] = fmaf(t, t, r[j]);
            }
        }
        sq[row] = ((r[0] + r[1]) + (r[2] + r[3])) + ((r[4] + r[5]) + (r[6] + r[7]));
    }

    uint4* dh = (uint4*)(HP + (size_t)row * C);
    uint4* dm = (uint4*)(MP + (size_t)row * C);
    uint4* dl = (uint4*)(LP + (size_t)row * C);
    #pragma unroll
    for (int c8 = 0; c8 < 8; c8++) {
        unsigned hq[4], mq[4], lq[4];
        #pragma unroll
        for (int e = 0; e < 4; e++) {
            float x0 = ((const float*)v)[c8 * 8 + 2 * e];
            float x1 = ((const float*)v)[c8 * 8 + 2 * e + 1];
            unsigned short h0 = f2bf(x0), h1 = f2bf(x1);
            float r10 = x0 - bf2f(h0), r11 = x1 - bf2f(h1);
            unsigned short m0 = f2bf(r10), m1 = f2bf(r11);
            float r20 = r10 - bf2f(m0), r21 = r11 - bf2f(m1);
            unsigned short l0 = f2bf(r20), l1 = f2bf(r21);
            hq[e] = (unsigned)h0 | ((unsigned)h1 << 16);
            mq[e] = (unsigned)m0 | ((unsigned)m1 << 16);
            lq[e] = (unsigned)l0 | ((unsigned)l1 << 16);
        }
        dh[c8] = make_uint4(hq[0], hq[1], hq[2], hq[3]);
        dm[c8] = make_uint4(mq[0], mq[1], mq[2], mq[3]);
        dl[c8] = make_uint4(lq[0], lq[1], lq[2], lq[3]);
    }
}

// ---------------------------------------------------------------------------
// 4-way merge of sorted 16-lists (in-LDS layout) -> 16 sorted keys to dst
// ---------------------------------------------------------------------------
__device__ __forceinline__ void merge4_store(const uint64_t* __restrict__ keys,
                                             int qloc, uint64_t* __restrict__ dst) {
    const uint64_t* K0 = keys + (qloc * 4 + 0) * 16;
    const uint64_t* K1 = keys + (qloc * 4 + 1) * 16;
    const uint64_t* K2 = keys + (qloc * 4 + 2) * 16;
    const uint64_t* K3 = keys + (qloc * 4 + 3) * 16;
    int p0 = 0, p1 = 0, p2 = 0, p3 = 0;
    uint64_t h0 = K0[0], h1 = K1[0], h2 = K2[0], h3 = K3[0];
    #pragma unroll
    for (int k = 0; k < K; k++) {
        uint64_t m01 = h0 < h1 ? h0 : h1;
        uint64_t m23 = h2 < h3 ? h2 : h3;
        uint64_t mv  = m01 < m23 ? m01 : m23;
        dst[k] = mv;
        if      (mv == h0) { ++p0; h0 = (p0 < 16) ? K0[p0] : ~0ull; }
        else if (mv == h1) { ++p1; h1 = (p1 < 16) ? K1[p1] : ~0ull; }
        else if (mv == h2) { ++p2; h2 = (p2 < 16) ? K2[p2] : ~0ull; }
        else               { ++p3; h3 = (p3 < 16) ? K3[p3] : ~0ull; }
    }
}

// ---------------------------------------------------------------------------
// Kernel 1: MFMA KNN, split-K x4 (1024 cands/half -> 1024 blocks, 3/CU
// resident). Engine byte-identical to round 13/15: dbuf LDS, 3-chain MFMA,
// Batcher-63 f64 fmin/fmax selection. Halves 0-1 -> keysA (ws),
// halves 2-3 -> keysB (d_out used as scratch, overwritten by mlp later).
// ---------------------------------------------------------------------------
__global__ __launch_bounds__(512, 2)
void knn_mfma_kernel(const unsigned short* __restrict__ HP,
                     const unsigned short* __restrict__ MP,
                     const unsigned short* __restrict__ LP,
                     const float* __restrict__ sqg,
                     uint64_t* __restrict__ keysgA, uint64_t* __restrict__ keysgB) {
    __shared__ __align__(16) char lds[49152];   // buf0 = [0,24K), buf1 = [24K,48K)

    const int s  = blockIdx.y;                  // candidate quarter (0..3)
    const int b  = blockIdx.z;
    const int i0 = blockIdx.x * 128;            // first query of block
    const int c0 = s * 1024;
    const unsigned short* Hb = HP + (size_t)b * N * C;
    const unsigned short* Mb = MP + (size_t)b * N * C;
    const unsigned short* Lb = LP + (size_t)b * N * C;
    const float* sqb = sqg + (size_t)b * N;

    const int tid = threadIdx.x;
    const int l   = tid & 63;
    const int w   = tid >> 6;                   // 0..7

    const int lr  = tid >> 3;                   // row 0..63
    const int lq  = tid & 7;                    // 16B chunk 0..7
    const int wbyte = (lr * 128 + lq * 16) ^ ((lr & 7) << 4);

    const double KMAX = __builtin_bit_cast(double, 0x7FEFFFFFFFFFFFFFull);

    // prefetch first candidate tile of this quarter (hides under Q staging)
    uint4 ph, pm, pl;
    {
        const size_t rb = (size_t)(c0 + lr) * C + lq * 8;
        ph = *(const uint4*)(Hb + rb);
        pm = *(const uint4*)(Mb + rb);
        pl = *(const uint4*)(Lb + rb);
    }

    {   // stage ALL 128 Q rows across both buffers (48KB)
        const size_t r0 = (size_t)(i0 + lr) * C + lq * 8;
        const size_t r1 = (size_t)(i0 + 64 + lr) * C + lq * 8;
        uint4 qh0 = *(const uint4*)(Hb + r0), qh1 = *(const uint4*)(Hb + r1);
        uint4 qm0 = *(const uint4*)(Mb + r0), qm1 = *(const uint4*)(Mb + r1);
        uint4 ql0 = *(const uint4*)(Lb + r0), ql1 = *(const uint4*)(Lb + r1);
        *(uint4*)(lds +              wbyte) = qh0;
        *(uint4*)(lds +  8192      + wbyte) = qm0;
        *(uint4*)(lds + 16384      + wbyte) = ql0;
        *(uint4*)(lds + 24576      + wbyte) = qh1;
        *(uint4*)(lds + 24576+8192 + wbyte) = qm1;
        *(uint4*)(lds + 24576+16384+ wbyte) = ql1;
    }
    __syncthreads();

    // B fragments (query), register-resident for the whole scan
    const int koff = (l >> 4) * 16;
    const int swzR = (l & 7) << 4;
    const int qrow = w * 16 + (l & 15);         // 0..127
    const char* qbuf = lds + ((qrow >> 6) ? 24576 : 0);
    const int qr6 = qrow & 63;
    const int qb0 = (qr6 * 128 + koff) ^ swzR;
    const int qb1 = (qr6 * 128 + 64 + koff) ^ swzR;
    short8 bh0 = *(const short8*)(qbuf + qb0),         bh1 = *(const short8*)(qbuf + qb1);
    short8 bm0 = *(const short8*)(qbuf +  8192 + qb0), bm1 = *(const short8*)(qbuf +  8192 + qb1);
    short8 bl0 = *(const short8*)(qbuf + 16384 + qb0), bl1 = *(const short8*)(qbuf + 16384 + qb1);

    const float sqq   = sqb[i0 + qrow];
    const int   qglob = i0 + qrow;
    const int   crow0 = (l >> 4) * 4;
    const int   dtile = i0 + ((w >> 2) << 6);   // wave-uniform diagonal tile

    __syncthreads();          // all waves finished reading Q

    // stage first candidate tile into buf0
    *(uint4*)(lds +         wbyte) = ph;
    *(uint4*)(lds +  8192 + wbyte) = pm;
    *(uint4*)(lds + 16384 + wbyte) = pl;
    {   // prefetch second tile
        const size_t rb = (size_t)(c0 + 64 + lr) * C + lq * 8;
        ph = *(const uint4*)(Hb + rb);
        pm = *(const uint4*)(Mb + rb);
        pl = *(const uint4*)(Lb + rb);
    }
    __syncthreads();          // first tile visible

    double bd[16];
    #pragma unroll
    for (int k = 0; k < 16; k++) bd[k] = KMAX;

    for (int t = 0; t < 16; t++) {
        const int j0 = c0 + t * 64;
        char* bufA = lds + ((t & 1) ? 24576 : 0);      // compute tile t
        char* bufB = lds + ((t & 1) ? 0 : 24576);      // stage tile t+1

        if (t < 15) {
            *(uint4*)(bufB +         wbyte) = ph;
            *(uint4*)(bufB +  8192 + wbyte) = pm;
            *(uint4*)(bufB + 16384 + wbyte) = pl;
        }
        if (t < 14) {
            const size_t rb = (size_t)(j0 + 128 + lr) * C + lq * 8;
            ph = *(const uint4*)(Hb + rb);
            pm = *(const uint4*)(Mb + rb);
            pl = *(const uint4*)(Lb + rb);
        }

        float4 sqm0 = *(const float4*)(sqb + j0 +      crow0);
        float4 sqm1 = *(const float4*)(sqb + j0 + 16 + crow0);
        float4 sqm2 = *(const float4*)(sqb + j0 + 32 + crow0);
        float4 sqm3 = *(const float4*)(sqb + j0 + 48 + crow0);

        double nk[16];

        #pragma unroll
        for (int m = 0; m < 4; m++) {
            const int arow = m * 16 + (l & 15);
            const int ab0 = (arow * 128 + koff) ^ swzR;
            const int ab1 = (arow * 128 + 64 + koff) ^ swzR;
            short8 ah0 = *(const short8*)(bufA + ab0);
            short8 ah1 = *(const short8*)(bufA + ab1);
            short8 am0 = *(const short8*)(bufA + 8192 + ab0);
            short8 am1 = *(const short8*)(bufA + 8192 + ab1);
            short8 al0 = *(const short8*)(bufA + 16384 + ab0);
            short8 al1 = *(const short8*)(bufA + 16384 + ab1);

            f32x4 acc1 = {0.f, 0.f, 0.f, 0.f};
            acc1 = __builtin_amdgcn_mfma_f32_16x16x32_bf16(am0, bm0, acc1, 0, 0, 0);
            acc1 = __builtin_amdgcn_mfma_f32_16x16x32_bf16(am1, bm1, acc1, 0, 0, 0);
            acc1 = __builtin_amdgcn_mfma_f32_16x16x32_bf16(ah0, bl0, acc1, 0, 0, 0);
            acc1 = __builtin_amdgcn_mfma_f32_16x16x32_bf16(ah1, bl1, acc1, 0, 0, 0);
            acc1 = __builtin_amdgcn_mfma_f32_16x16x32_bf16(al0, bh0, acc1, 0, 0, 0);
            f32x4 acc2 = {0.f, 0.f, 0.f, 0.f};
            acc2 = __builtin_amdgcn_mfma_f32_16x16x32_bf16(al1, bh1, acc2, 0, 0, 0);
            acc2 = __builtin_amdgcn_mfma_f32_16x16x32_bf16(ah0, bm0, acc2, 0, 0, 0);
            acc2 = __builtin_amdgcn_mfma_f32_16x16x32_bf16(ah1, bm1, acc2, 0, 0, 0);
            acc2 = __builtin_amdgcn_mfma_f32_16x16x32_bf16(am0, bh0, acc2, 0, 0, 0);
            acc2 = __builtin_amdgcn_mfma_f32_16x16x32_bf16(am1, bh1, acc2, 0, 0, 0);
            f32x4 acch = {0.f, 0.f, 0.f, 0.f};
            acch = __builtin_amdgcn_mfma_f32_16x16x32_bf16(ah0, bh0, acch, 0, 0, 0);
            acch = __builtin_amdgcn_mfma_f32_16x16x32_bf16(ah1, bh1, acch, 0, 0, 0);

            float4 sqm = (m == 0) ? sqm0 : (m == 1) ? sqm1 : (m == 2) ? sqm2 : sqm3;
            #pragma unroll
            for (int r = 0; r < 4; r++) {
                float sqc = (r == 0) ? sqm.x : (r == 1) ? sqm.y : (r == 2) ? sqm.z : sqm.w;
                float gg = acch[r] + (acc1[r] + acc2[r]);
                float d2 = fmaf(-2.0f, gg, sqq + sqc);
                d2 = fmaxf(d2, 0.0f);
                nk[m * 4 + r] = pack_key(d2, (unsigned)(j0 + m * 16 + crow0 + r));
            }
        }

        // diagonal tile only: kill self-match (wave-uniform branch)
        if (j0 == dtile) {
            #pragma unroll
            for (int m = 0; m < 4; m++)
                #pragma unroll
                for (int r = 0; r < 4; r++)
                    if ((j0 + m * 16 + crow0 + r) == qglob) nk[m * 4 + r] = KMAX;
        }

        // ---- Batcher odd-even mergesort, n=16, DESCENDING (63 comparators) ----
        #pragma unroll
        for (int p = 1; p < 16; p <<= 1) {
            #pragma unroll
            for (int kk = p; kk >= 1; kk >>= 1) {
                #pragma unroll
                for (int j = kk % p; j <= 16 - 1 - kk; j += 2 * kk) {
                    #pragma unroll
                    for (int i = 0; i <= ((kk - 1 < 16 - j - kk - 1) ? kk - 1 : 16 - j - kk - 1); i++) {
                        if ((i + j) / (2 * p) == (i + j + kk) / (2 * p)) {
                            double a = nk[i + j], c2 = nk[i + j + kk];
                            nk[i + j]      = fmax(a, c2);   // descending
                            nk[i + j + kk] = fmin(a, c2);
                        }
                    }
                }
            }
        }
        // ---- lowest-16 of (bd asc ++ nk desc): elementwise min ----
        #pragma unroll
        for (int i = 0; i < 16; i++) bd[i] = fmin(bd[i], nk[i]);
        // ---- bd bitonic -> ascending cleanup (strides 8,4,2,1) ----
        #pragma unroll
        for (int j = 8; j > 0; j >>= 1) {
            #pragma unroll
            for (int i = 0; i < 16; i++) {
                int ixj = i ^ j;
                if (ixj > i) {
                    double a = bd[i], c2 = bd[ixj];
                    bd[i]   = fmin(a, c2);
                    bd[ixj] = fmax(a, c2);
                }
            }
        }

        __syncthreads();       // tile t+1 staged & prior reads done
    }

    // ---- epilogue: two 64-query passes (32KB key scratch each) ----
    uint64_t* keys = (uint64_t*)lds;
    uint64_t* base0 = (s < 2) ? keysgA : keysgB;
    const int  soff = (s & 1) * 16;
    if (w < 4) {               // pass A: queries i0..i0+63
        const int qloc = w * 16 + (l & 15);
        const int base = (qloc * 4 + (l >> 4)) * 16;
        #pragma unroll
        for (int k = 0; k < 16; k++)
            keys[base + k] = __builtin_bit_cast(uint64_t, bd[k]);
    }
    __syncthreads();
    if (tid < 64)
        merge4_store(keys, tid, base0 + ((size_t)b * N + i0 + tid) * 32 + soff);
    __syncthreads();
    if (w >= 4) {              // pass B: queries i0+64..i0+127
        const int qloc = (w - 4) * 16 + (l & 15);
        const int base = (qloc * 4 + (l >> 4)) * 16;
        #pragma unroll
        for (int k = 0; k < 16; k++)
            keys[base + k] = __builtin_bit_cast(uint64_t, bd[k]);
    }
    __syncthreads();
    if (tid < 64)
        merge4_store(keys, tid, base0 + ((size_t)b * N + i0 + 64 + tid) * 32 + soff);
}

// ---------------------------------------------------------------------------
// Kernel 1b: final 4-way merge of the four quarters, one thread per query
// ---------------------------------------------------------------------------
__global__ __launch_bounds__(256)
void knn_merge_kernel(const uint64_t* __restrict__ keysgA,
                      const uint64_t* __restrict__ keysgB, int* __restrict__ knn) {
    const int q = blockIdx.x * 256 + threadIdx.x;     // 0..B*N-1
    const uint64_t* P0 = keysgA + (size_t)q * 32;
    const uint64_t* P1 = P0 + 16;
    const uint64_t* P2 = keysgB + (size_t)q * 32;
    const uint64_t* P3 = P2 + 16;
    int p0 = 0, p1 = 0, p2 = 0, p3 = 0;
    uint64_t h0 = P0[0], h1 = P1[0], h2 = P2[0], h3 = P3[0];
    int* dst = knn + (size_t)q * K;
    #pragma unroll
    for (int k = 0; k < K; k++) {
        uint64_t m01 = h0 < h1 ? h0 : h1;
        uint64_t m23 = h2 < h3 ? h2 : h3;
        uint64_t mv  = m01 < m23 ? m01 : m23;
        dst[k] = (int)(mv & 0xFFFFFFFFu);
        if      (mv == h0) { ++p0; h0 = (p0 < 16) ? P0[p0] : ~0ull; }
        else if (mv == h1) { ++p1; h1 = (p1 < 16) ? P1[p1] : ~0ull; }
        else if (mv == h2) { ++p2; h2 = (p2 < 16) ? P2[p2] : ~0ull; }
        else               { ++p3; h3 = (p3 < 16) ? P3[p3] : ~0ull; }
    }
}

// ---------------------------------------------------------------------------
// Kernel 2: MFMA MLP (round-15 numerics) with FULL one-query-ahead prefetch:
// neighbor rows + central fp32 + central bf16 planes all double-buffered.
// ---------------------------------------------------------------------------
__device__ __forceinline__ float gelu_fast(float x) {
    float az = fabsf(x) * 0.70710678118654752440f;
    float t  = __builtin_amdgcn_rcpf(fmaf(0.3275911f, az, 1.0f));
    float p  = t * fmaf(t, fmaf(t, fmaf(t, fmaf(t, 1.061405429f, -1.453152027f),
                                        1.421413741f), -0.284496736f), 0.254829592f);
    float e  = p * __builtin_amdgcn_exp2f(-az * az * 1.44269504088896f); // 1-erf(az)
    float g  = 0.5f * x;
    return (x >= 0.0f) ? g * (2.0f - e) : g * e;
}

#define QPW 4

__global__ __launch_bounds__(256)
void mlp_mfma_kernel(const float* __restrict__ F,
                     const unsigned short* __restrict__ HP,
                     const unsigned short* __restrict__ MP,
                     const int* __restrict__ knn,
                     const float* __restrict__ W1, const float* __restrict__ b1,
                     const float* __restrict__ W2, const float* __restrict__ b2,
                     float* __restrict__ out) {
    __shared__ __align__(16) unsigned short W1h[64 * 128];   // 16KB
    __shared__ __align__(16) unsigned short W1m[64 * 128];   // 16KB
    __shared__ __align__(16) unsigned short hbh[4][1024];    // per-wave h hi (8KB)

    const int tid = threadIdx.x;
    const int l   = tid & 63;
    const int w   = tid >> 6;

    const int cb    = (l >> 4) * 8;
    const int swzL  = (l & 15) << 4;
    const int qbase = (blockIdx.x * 4 + w) * QPW;
    char* hbh_w = (char*)&hbh[w][0];

    // all knn indices for this wave's 4 queries, issued immediately
    int nbs[QPW];
    #pragma unroll
    for (int jq = 0; jq < QPW; jq++)
        nbs[jq] = knn[(size_t)(qbase + jq) * K + (l & 15)];

    for (int e = tid; e < 8192; e += 256) {   // W1 image: [n][k], swizzled, 2-term
        const int n = e & 63, k = e >> 6;
        const int srcrow = (k < 64) ? (64 + k) : (k - 64);
        float x = W1[srcrow * 64 + n];
        unsigned short hh = f2bf(x);
        unsigned short mm = f2bf(x - bf2f(hh));
        const int byte = (n * 256 + k * 2) ^ ((n & 15) << 4);
        *(unsigned short*)((char*)W1h + byte) = hh;
        *(unsigned short*)((char*)W1m + byte) = mm;
    }

    // W2 fragments in registers: hi only (1-term layer 2)
    short8 B2h[4][2];
    float b1v[4], b2v[4];
    {
        const int n = (l & 15);
        #pragma unroll
        for (int nt = 0; nt < 4; nt++) {
            const int nn = nt * 16 + n;
            b1v[nt] = b1[nn];
            b2v[nt] = b2[nn];
            #pragma unroll
            for (int c = 0; c < 2; c++) {
                const int k0 = c * 32 + (l >> 4) * 8;
                short8 vh;
                #pragma unroll
                for (int jj = 0; jj < 8; jj++)
                    vh[jj] = (short)f2bf(W2[(k0 + jj) * 64 + nn]);
                B2h[nt][c] = vh;
            }
        }
    }
    __syncthreads();

    // full per-query prefetch double buffers
    float4 pnA0[2], pnA1[2], pnB0[2], pnB1[2];      // neighbor fp32
    float4 pcA0[2], pcA1[2], pcB0[2], pcB1[2];      // central fp32
    short8 pah0[2], pah1[2], pam0[2], pam1[2];      // central planes
#define LOADQ(s_, jq_) { \
        const int q_  = qbase + (jq_); \
        const int b_  = q_ >> 12; \
        const int ci_ = q_ & (N - 1); \
        const float*          Fb_  = F  + (size_t)b_ * N * C; \
        const unsigned short* HPb_ = HP + (size_t)b_ * N * C; \
        const unsigned short* MPb_ = MP + (size_t)b_ * N * C; \
        const size_t nr_ = (size_t)nbs[jq_] * C; \
        pnA0[s_] = *(const float4*)(Fb_ + nr_ + cb); \
        pnA1[s_] = *(const float4*)(Fb_ + nr_ + cb + 4); \
        pnB0[s_] = *(const float4*)(Fb_ + nr_ + 32 + cb); \
        pnB1[s_] = *(const float4*)(Fb_ + nr_ + 36 + cb); \
        pcA0[s_] = *(const float4*)(Fb_ + (size_t)ci_ * C + cb); \
        pcA1[s_] = *(const float4*)(Fb_ + (size_t)ci_ * C + cb + 4); \
        pcB0[s_] = *(const float4*)(Fb_ + (size_t)ci_ * C + 32 + cb); \
        pcB1[s_] = *(const float4*)(Fb_ + (size_t)ci_ * C + 36 + cb); \
        pah0[s_] = *(const short8*)(HPb_ + (size_t)ci_ * C + cb); \
        pah1[s_] = *(const short8*)(HPb_ + (size_t)ci_ * C + 32 + cb); \
        pam0[s_] = *(const short8*)(MPb_ + (size_t)ci_ * C + cb); \
        pam1[s_] = *(const short8*)(MPb_ + (size_t)ci_ * C + 32 + cb); \
    }
    LOADQ(0, 0);

    #pragma unroll
    for (int jq = 0; jq < QPW; jq++) {
        const int sbuf = jq & 1;
        if (jq + 1 < QPW) LOADQ(sbuf ^ 1, jq + 1);

        const int q = qbase + jq;

        float4 cA0 = pcA0[sbuf], cA1 = pcA1[sbuf];
        float4 cB0 = pcB0[sbuf], cB1 = pcB1[sbuf];
        float4 nA0 = pnA0[sbuf], nA1 = pnA1[sbuf];
        float4 nB0 = pnB0[sbuf], nB1 = pnB1[sbuf];
        short8 ach0 = pah0[sbuf], ach1 = pah1[sbuf];
        short8 acm0 = pam0[sbuf], acm1 = pam1[sbuf];

        short8 adh0, adm0, adh1, adm1;
        {
            float d0[8] = {nA0.x - cA0.x, nA0.y - cA0.y, nA0.z - cA0.z, nA0.w - cA0.w,
                           nA1.x - cA1.x, nA1.y - cA1.y, nA1.z - cA1.z, nA1.w - cA1.w};
            float d1[8] = {nB0.x - cB0.x, nB0.y - cB0.y, nB0.z - cB0.z, nB0.w - cB0.w,
                           nB1.x - cB1.x, nB1.y - cB1.y, nB1.z - cB1.z, nB1.w - cB1.w};
            #pragma unroll
            for (int jj = 0; jj < 8; jj++) {
                unsigned short h0 = f2bf(d0[jj]);
                adh0[jj] = (short)h0; adm0[jj] = (short)f2bf(d0[jj] - bf2f(h0));
                unsigned short h1 = f2bf(d1[jj]);
                adh1[jj] = (short)h1; adm1[jj] = (short)f2bf(d1[jj] - bf2f(h1));
            }
        }

        // ---- layer 1 (2-term) ----
        #pragma unroll
        for (int nt = 0; nt < 4; nt++) {
            const int rowb = (nt * 16 + (l & 15)) * 256 + (l >> 4) * 16;
            f32x4 a1 = {0.f, 0.f, 0.f, 0.f};
            f32x4 a2 = {0.f, 0.f, 0.f, 0.f};
            #pragma unroll
            for (int kc = 0; kc < 4; kc++) {
                const int byte = (rowb + kc * 64) ^ swzL;
                short8 Bh = *(const short8*)((char*)W1h + byte);
                short8 Bm = *(const short8*)((char*)W1m + byte);
                short8 Ah = (kc == 0) ? adh0 : (kc == 1) ? adh1 : (kc == 2) ? ach0 : ach1;
                short8 Am = (kc == 0) ? adm0 : (kc == 1) ? adm1 : (kc == 2) ? acm0 : acm1;
                a1 = __builtin_amdgcn_mfma_f32_16x16x32_bf16(Ah, Bh, a1, 0, 0, 0);
                a2 = __builtin_amdgcn_mfma_f32_16x16x32_bf16(Ah, Bm, a2, 0, 0, 0);
                a2 = __builtin_amdgcn_mfma_f32_16x16x32_bf16(Am, Bh, a2, 0, 0, 0);
            }
            // gelu + hi-only transpose-store
            #pragma unroll
            for (int r = 0; r < 4; r++) {
                const int row = (l >> 4) * 4 + r;
                const int col = nt * 16 + (l & 15);
                float hv = gelu_fast(a1[r] + a2[r] + b1v[nt]);
                const int byte = (row * 128 + col * 2) ^ ((row & 7) << 4);
                *(unsigned short*)(hbh_w + byte) = f2bf(hv);
            }
        }

        asm volatile("s_waitcnt lgkmcnt(0)" ::: "memory");
        __builtin_amdgcn_sched_barrier(0);

        // ---- layer 2 (1-term): A = h-hi rows, B = W2-hi register frags ----
        short8 Ah2[2];
        #pragma unroll
        for (int kc = 0; kc < 2; kc++) {
            const int byte = ((l & 15) * 128 + kc * 64 + (l >> 4) * 16) ^ (((l & 15) & 7) << 4);
            Ah2[kc] = *(const short8*)(hbh_w + byte);
        }
        #pragma unroll
        for (int nt = 0; nt < 4; nt++) {
            f32x4 a1 = {0.f, 0.f, 0.f, 0.f};
            #pragma unroll
            for (int kc = 0; kc < 2; kc++)
                a1 = __builtin_amdgcn_mfma_f32_16x16x32_bf16(Ah2[kc], B2h[nt][kc], a1, 0, 0, 0);
            float mx = -INFINITY;
            #pragma unroll
            for (int r = 0; r < 4; r++)
                mx = fmaxf(mx, gelu_fast(a1[r] + b2v[nt]));
            mx = fmaxf(mx, __shfl_xor(mx, 16));
            mx = fmaxf(mx, __shfl_xor(mx, 32));
            if (l < 16) out[(size_t)q * D + nt * 16 + l] = mx;
        }
    }
#undef LOADQ
}

// ---------------------------------------------------------------------------
extern "C" void kernel_launch(void* const* d_in, const int* in_sizes, int n_in,
                              void* d_out, int out_size, void* d_ws, size_t ws_size,
                              hipStream_t stream) {
    const float* F  = (const float*)d_in[0];
    const float* W1 = (const float*)d_in[1];
    const float* b1 = (const float*)d_in[2];
    const float* W2 = (const float*)d_in[3];
    const float* b2 = (const float*)d_in[4];
    float* out = (float*)d_out;

    char* ws = (char*)d_ws;
    float*          sq    = (float*)ws;                             // 128 KB
    uint64_t*       keysA = (uint64_t*)(ws + (128 << 10));          // 8 MB (quarters 0,1)
    uint64_t*       keysB = (uint64_t*)d_out;                       // 8 MB scratch (quarters 2,3)
    unsigned short* HP    = (unsigned short*)(ws + (8320 << 10));   // 4 MB
    unsigned short* MP    = (unsigned short*)(ws + (12416 << 10));  // 4 MB
    unsigned short* LP    = (unsigned short*)(ws + (16512 << 10));  // 4 MB
    int*            knn   = (int*)LP;   // LP dead after knn_mfma pass

    prep_kernel<<<dim3(B * N / 256), 256, 0, stream>>>(F, sq, HP, MP, LP);
    knn_mfma_kernel<<<dim3(N / 128, 4, B), 512, 0, stream>>>(HP, MP, LP, sq, keysA, keysB);
    knn_merge_kernel<<<dim3(B * N / 256), 256, 0, stream>>>(keysA, keysB, knn);
    mlp_mfma_kernel<<<dim3(B * N / (4 * QPW)), 256, 0, stream>>>(
        F, HP, MP, knn, W1, b1, W2, b2, out);
}

// Round 17
// 253.879 us; speedup vs baseline: 1.0510x; 1.0510x over previous
//
#include <hip/hip_runtime.h>
#include <math.h>
#include <stdint.h>

#define B 8
#define N 4096
#define C 64
#define D 64
#define K 16

typedef __attribute__((ext_vector_type(8))) short short8;
typedef __attribute__((ext_vector_type(4))) float f32x4;

// ---------------------------------------------------------------------------
// bf16 helpers
// ---------------------------------------------------------------------------
__device__ __forceinline__ unsigned short f2bf(float x) {
    unsigned u = __float_as_uint(x);
    unsigned r = (u + 0x7FFFu + ((u >> 16) & 1u)) >> 16;   // RNE
    return (unsigned short)r;
}
__device__ __forceinline__ float bf2f(unsigned short h) {
    return __uint_as_float(((unsigned)h) << 16);
}

// key = (d2bits<<32)|idx reinterpreted as double. d2 finite >=0 -> positive
// finite double -> IEEE ordering == integer ordering (exact tie-break kept).
// f64 fmin/fmax comparators measured FASTER than u64 cmp+cndmask (round 12).
__device__ __forceinline__ double pack_key(float d2, unsigned idx) {
    uint2 u; u.x = idx; u.y = __float_as_uint(d2);
    return __builtin_bit_cast(double, u);
}

// ---------------------------------------------------------------------------
// Kernel 0: block-specialized prep.
// Blocks 0..127   : per-row sqnorm (round-1 arithmetic, byte-identical).
// Blocks 128..383 : 3-term bf16 split at HALF-ROW granularity (2x threads;
//                   per-element arithmetic and output bits identical).
// ---------------------------------------------------------------------------
__global__ __launch_bounds__(256)
void prep_kernel(const float* __restrict__ F, float* __restrict__ sq,
                 unsigned short* __restrict__ HP, unsigned short* __restrict__ MP,
                 unsigned short* __restrict__ LP) {
    if (blockIdx.x < 128) {
        const int row = blockIdx.x * 256 + threadIdx.x;
        const float4* src = (const float4*)(F + (size_t)row * C);
        float4 v[16];
        #pragma unroll
        for (int q = 0; q < 16; q++) v[q] = src[q];

        float r[8];
        #pragma unroll
        for (int j = 0; j < 8; j++) {
            float t = ((const float*)v)[j];
            r[j] = t * t;
        }
        #pragma unroll
        for (int m = 1; m < 8; m++) {
            #pragma unroll
            for (int j = 0; j < 8; j++) {
                float t = ((const float*)v)[8 * m + j];
                r[j] = fmaf(t, t, r[j]);
            }
        }
        sq[row] = ((r[0] + r[1]) + (r[2] + r[3])) + ((r[4] + r[5]) + (r[6] + r[7]));
    } else {
        const int hr   = (blockIdx.x - 128) * 256 + threadIdx.x;  // 0..65535
        const int row  = hr >> 1;
        const int half = hr & 1;
        const float4* src = (const float4*)(F + (size_t)row * C + half * 32);
        float4 v[8];
        #pragma unroll
        for (int q = 0; q < 8; q++) v[q] = src[q];

        uint4* dh = (uint4*)(HP + (size_t)row * C) + half * 4;
        uint4* dm = (uint4*)(MP + (size_t)row * C) + half * 4;
        uint4* dl = (uint4*)(LP + (size_t)row * C) + half * 4;
        #pragma unroll
        for (int c8 = 0; c8 < 4; c8++) {          // 8 values per chunk
            unsigned hq[4], mq[4], lq[4];
            #pragma unroll
            for (int e = 0; e < 4; e++) {
                float x0 = ((const float*)v)[c8 * 8 + 2 * e];
                float x1 = ((const float*)v)[c8 * 8 + 2 * e + 1];
                unsigned short h0 = f2bf(x0), h1 = f2bf(x1);
                float r10 = x0 - bf2f(h0), r11 = x1 - bf2f(h1);
                unsigned short m0 = f2bf(r10), m1 = f2bf(r11);
                float r20 = r10 - bf2f(m0), r21 = r11 - bf2f(m1);
                unsigned short l0 = f2bf(r20), l1 = f2bf(r21);
                hq[e] = (unsigned)h0 | ((unsigned)h1 << 16);
                mq[e] = (unsigned)m0 | ((unsigned)m1 << 16);
                lq[e] = (unsigned)l0 | ((unsigned)l1 << 16);
            }
            dh[c8] = make_uint4(hq[0], hq[1], hq[2], hq[3]);
            dm[c8] = make_uint4(mq[0], mq[1], mq[2], mq[3]);
            dl[c8] = make_uint4(lq[0], lq[1], lq[2], lq[3]);
        }
    }
}

// ---------------------------------------------------------------------------
// 4-way merge of sorted lists for one query -> 16 sorted keys to dst
// ---------------------------------------------------------------------------
__device__ __forceinline__ void merge4_store(const uint64_t* __restrict__ keys,
                                             int qloc, uint64_t* __restrict__ dst) {
    const uint64_t* K0 = keys + (qloc * 4 + 0) * 16;
    const uint64_t* K1 = keys + (qloc * 4 + 1) * 16;
    const uint64_t* K2 = keys + (qloc * 4 + 2) * 16;
    const uint64_t* K3 = keys + (qloc * 4 + 3) * 16;
    int p0 = 0, p1 = 0, p2 = 0, p3 = 0;
    uint64_t h0 = K0[0], h1 = K1[0], h2 = K2[0], h3 = K3[0];
    #pragma unroll
    for (int k = 0; k < K; k++) {
        uint64_t m01 = h0 < h1 ? h0 : h1;
        uint64_t m23 = h2 < h3 ? h2 : h3;
        uint64_t mv  = m01 < m23 ? m01 : m23;
        dst[k] = mv;
        if      (mv == h0) { ++p0; h0 = (p0 < 16) ? K0[p0] : ~0ull; }
        else if (mv == h1) { ++p1; h1 = (p1 < 16) ? K1[p1] : ~0ull; }
        else if (mv == h2) { ++p2; h2 = (p2 < 16) ? K2[p2] : ~0ull; }
        else               { ++p3; h3 = (p3 < 16) ? K3[p3] : ~0ull; }
    }
}

// ---------------------------------------------------------------------------
// Kernel 1: MFMA KNN (round-13/15 proven, byte-identical). 512 threads /
// 8 waves, 128 queries/block, split-K x2, Batcher-63 f64 fmin/fmax selection.
// ---------------------------------------------------------------------------
__global__ __launch_bounds__(512, 2)
void knn_mfma_kernel(const unsigned short* __restrict__ HP,
                     const unsigned short* __restrict__ MP,
                     const unsigned short* __restrict__ LP,
                     const float* __restrict__ sqg, uint64_t* __restrict__ keysg) {
    __shared__ __align__(16) char lds[49152];   // buf0 = [0,24K), buf1 = [24K,48K)

    const int s  = blockIdx.y;                  // candidate half
    const int b  = blockIdx.z;
    const int i0 = blockIdx.x * 128;            // first query of block
    const int c0 = s * 2048;
    const unsigned short* Hb = HP + (size_t)b * N * C;
    const unsigned short* Mb = MP + (size_t)b * N * C;
    const unsigned short* Lb = LP + (size_t)b * N * C;
    const float* sqb = sqg + (size_t)b * N;

    const int tid = threadIdx.x;
    const int l   = tid & 63;
    const int w   = tid >> 6;                   // 0..7

    const int lr  = tid >> 3;                   // row 0..63
    const int lq  = tid & 7;                    // 16B chunk 0..7
    const int wbyte = (lr * 128 + lq * 16) ^ ((lr & 7) << 4);

    const double KMAX = __builtin_bit_cast(double, 0x7FEFFFFFFFFFFFFFull);

    // prefetch first candidate tile of this half (hides under Q staging)
    uint4 ph, pm, pl;
    {
        const size_t rb = (size_t)(c0 + lr) * C + lq * 8;
        ph = *(const uint4*)(Hb + rb);
        pm = *(const uint4*)(Mb + rb);
        pl = *(const uint4*)(Lb + rb);
    }

    {   // stage ALL 128 Q rows across both buffers (48KB)
        const size_t r0 = (size_t)(i0 + lr) * C + lq * 8;
        const size_t r1 = (size_t)(i0 + 64 + lr) * C + lq * 8;
        uint4 qh0 = *(const uint4*)(Hb + r0), qh1 = *(const uint4*)(Hb + r1);
        uint4 qm0 = *(const uint4*)(Mb + r0), qm1 = *(const uint4*)(Mb + r1);
        uint4 ql0 = *(const uint4*)(Lb + r0), ql1 = *(const uint4*)(Lb + r1);
        *(uint4*)(lds +              wbyte) = qh0;
        *(uint4*)(lds +  8192      + wbyte) = qm0;
        *(uint4*)(lds + 16384      + wbyte) = ql0;
        *(uint4*)(lds + 24576      + wbyte) = qh1;
        *(uint4*)(lds + 24576+8192 + wbyte) = qm1;
        *(uint4*)(lds + 24576+16384+ wbyte) = ql1;
    }
    __syncthreads();

    // B fragments (query), register-resident for the whole scan
    const int koff = (l >> 4) * 16;
    const int swzR = (l & 7) << 4;
    const int qrow = w * 16 + (l & 15);         // 0..127
    const char* qbuf = lds + ((qrow >> 6) ? 24576 : 0);
    const int qr6 = qrow & 63;
    const int qb0 = (qr6 * 128 + koff) ^ swzR;
    const int qb1 = (qr6 * 128 + 64 + koff) ^ swzR;
    short8 bh0 = *(const short8*)(qbuf + qb0),         bh1 = *(const short8*)(qbuf + qb1);
    short8 bm0 = *(const short8*)(qbuf +  8192 + qb0), bm1 = *(const short8*)(qbuf +  8192 + qb1);
    short8 bl0 = *(const short8*)(qbuf + 16384 + qb0), bl1 = *(const short8*)(qbuf + 16384 + qb1);

    const float sqq   = sqb[i0 + qrow];
    const int   qglob = i0 + qrow;
    const int   crow0 = (l >> 4) * 4;
    const int   dtile = i0 + ((w >> 2) << 6);   // wave-uniform diagonal tile

    __syncthreads();          // all waves finished reading Q

    // stage first candidate tile into buf0
    *(uint4*)(lds +         wbyte) = ph;
    *(uint4*)(lds +  8192 + wbyte) = pm;
    *(uint4*)(lds + 16384 + wbyte) = pl;
    {   // prefetch second tile
        const size_t rb = (size_t)(c0 + 64 + lr) * C + lq * 8;
        ph = *(const uint4*)(Hb + rb);
        pm = *(const uint4*)(Mb + rb);
        pl = *(const uint4*)(Lb + rb);
    }
    __syncthreads();          // first tile visible

    double bd[16];
    #pragma unroll
    for (int k = 0; k < 16; k++) bd[k] = KMAX;

    for (int t = 0; t < 32; t++) {
        const int j0 = c0 + t * 64;
        char* bufA = lds + ((t & 1) ? 24576 : 0);      // compute tile t
        char* bufB = lds + ((t & 1) ? 0 : 24576);      // stage tile t+1

        if (t < 31) {
            *(uint4*)(bufB +         wbyte) = ph;
            *(uint4*)(bufB +  8192 + wbyte) = pm;
            *(uint4*)(bufB + 16384 + wbyte) = pl;
        }
        if (t < 30) {
            const size_t rb = (size_t)(j0 + 128 + lr) * C + lq * 8;
            ph = *(const uint4*)(Hb + rb);
            pm = *(const uint4*)(Mb + rb);
            pl = *(const uint4*)(Lb + rb);
        }

        float4 sqm0 = *(const float4*)(sqb + j0 +      crow0);
        float4 sqm1 = *(const float4*)(sqb + j0 + 16 + crow0);
        float4 sqm2 = *(const float4*)(sqb + j0 + 32 + crow0);
        float4 sqm3 = *(const float4*)(sqb + j0 + 48 + crow0);

        double nk[16];

        #pragma unroll
        for (int m = 0; m < 4; m++) {
            const int arow = m * 16 + (l & 15);
            const int ab0 = (arow * 128 + koff) ^ swzR;
            const int ab1 = (arow * 128 + 64 + koff) ^ swzR;
            short8 ah0 = *(const short8*)(bufA + ab0);
            short8 ah1 = *(const short8*)(bufA + ab1);
            short8 am0 = *(const short8*)(bufA + 8192 + ab0);
            short8 am1 = *(const short8*)(bufA + 8192 + ab1);
            short8 al0 = *(const short8*)(bufA + 16384 + ab0);
            short8 al1 = *(const short8*)(bufA + 16384 + ab1);

            f32x4 acc1 = {0.f, 0.f, 0.f, 0.f};
            acc1 = __builtin_amdgcn_mfma_f32_16x16x32_bf16(am0, bm0, acc1, 0, 0, 0);
            acc1 = __builtin_amdgcn_mfma_f32_16x16x32_bf16(am1, bm1, acc1, 0, 0, 0);
            acc1 = __builtin_amdgcn_mfma_f32_16x16x32_bf16(ah0, bl0, acc1, 0, 0, 0);
            acc1 = __builtin_amdgcn_mfma_f32_16x16x32_bf16(ah1, bl1, acc1, 0, 0, 0);
            acc1 = __builtin_amdgcn_mfma_f32_16x16x32_bf16(al0, bh0, acc1, 0, 0, 0);
            f32x4 acc2 = {0.f, 0.f, 0.f, 0.f};
            acc2 = __builtin_amdgcn_mfma_f32_16x16x32_bf16(al1, bh1, acc2, 0, 0, 0);
            acc2 = __builtin_amdgcn_mfma_f32_16x16x32_bf16(ah0, bm0, acc2, 0, 0, 0);
            acc2 = __builtin_amdgcn_mfma_f32_16x16x32_bf16(ah1, bm1, acc2, 0, 0, 0);
            acc2 = __builtin_amdgcn_mfma_f32_16x16x32_bf16(am0, bh0, acc2, 0, 0, 0);
            acc2 = __builtin_amdgcn_mfma_f32_16x16x32_bf16(am1, bh1, acc2, 0, 0, 0);
            f32x4 acch = {0.f, 0.f, 0.f, 0.f};
            acch = __builtin_amdgcn_mfma_f32_16x16x32_bf16(ah0, bh0, acch, 0, 0, 0);
            acch = __builtin_amdgcn_mfma_f32_16x16x32_bf16(ah1, bh1, acch, 0, 0, 0);

            float4 sqm = (m == 0) ? sqm0 : (m == 1) ? sqm1 : (m == 2) ? sqm2 : sqm3;
            #pragma unroll
            for (int r = 0; r < 4; r++) {
                float sqc = (r == 0) ? sqm.x : (r == 1) ? sqm.y : (r == 2) ? sqm.z : sqm.w;
                float gg = acch[r] + (acc1[r] + acc2[r]);
                float d2 = fmaf(-2.0f, gg, sqq + sqc);
                d2 = fmaxf(d2, 0.0f);
                nk[m * 4 + r] = pack_key(d2, (unsigned)(j0 + m * 16 + crow0 + r));
            }
        }

        // diagonal tile only: kill self-match (wave-uniform branch)
        if (j0 == dtile) {
            #pragma unroll
            for (int m = 0; m < 4; m++)
                #pragma unroll
                for (int r = 0; r < 4; r++)
                    if ((j0 + m * 16 + crow0 + r) == qglob) nk[m * 4 + r] = KMAX;
        }

        // ---- Batcher odd-even mergesort, n=16, DESCENDING (63 comparators,
        //      f64 fmin/fmax: 2 instr/CAS — measured fastest, round 11/12) ----
        #pragma unroll
        for (int p = 1; p < 16; p <<= 1) {
            #pragma unroll
            for (int kk = p; kk >= 1; kk >>= 1) {
                #pragma unroll
                for (int j = kk % p; j <= 16 - 1 - kk; j += 2 * kk) {
                    #pragma unroll
                    for (int i = 0; i <= ((kk - 1 < 16 - j - kk - 1) ? kk - 1 : 16 - j - kk - 1); i++) {
                        if ((i + j) / (2 * p) == (i + j + kk) / (2 * p)) {
                            double a = nk[i + j], c2 = nk[i + j + kk];
                            nk[i + j]      = fmax(a, c2);   // descending
                            nk[i + j + kk] = fmin(a, c2);
                        }
                    }
                }
            }
        }
        // ---- lowest-16 of (bd asc ++ nk desc): elementwise min ----
        #pragma unroll
        for (int i = 0; i < 16; i++) bd[i] = fmin(bd[i], nk[i]);
        // ---- bd bitonic -> ascending cleanup (strides 8,4,2,1) ----
        #pragma unroll
        for (int j = 8; j > 0; j >>= 1) {
            #pragma unroll
            for (int i = 0; i < 16; i++) {
                int ixj = i ^ j;
                if (ixj > i) {
                    double a = bd[i], c2 = bd[ixj];
                    bd[i]   = fmin(a, c2);
                    bd[ixj] = fmax(a, c2);
                }
            }
        }

        __syncthreads();       // tile t+1 staged & prior reads done
    }

    // ---- epilogue: two 64-query passes (32KB key scratch each) ----
    uint64_t* keys = (uint64_t*)lds;
    if (w < 4) {               // pass A: queries i0..i0+63
        const int qloc = w * 16 + (l & 15);
        const int base = (qloc * 4 + (l >> 4)) * 16;
        #pragma unroll
        for (int k = 0; k < 16; k++)
            keys[base + k] = __builtin_bit_cast(uint64_t, bd[k]);
    }
    __syncthreads();
    if (tid < 64)
        merge4_store(keys, tid, keysg + ((size_t)b * N + i0 + tid) * 32 + s * 16);
    __syncthreads();
    if (w >= 4) {              // pass B: queries i0+64..i0+127
        const int qloc = (w - 4) * 16 + (l & 15);
        const int base = (qloc * 4 + (l >> 4)) * 16;
        #pragma unroll
        for (int k = 0; k < 16; k++)
            keys[base + k] = __builtin_bit_cast(uint64_t, bd[k]);
    }
    __syncthreads();
    if (tid < 64)
        merge4_store(keys, tid, keysg + ((size_t)b * N + i0 + 64 + tid) * 32 + s * 16);
}

// ---------------------------------------------------------------------------
// Kernel 1b: final 2-way merge of the two halves, one thread per query
// ---------------------------------------------------------------------------
__global__ __launch_bounds__(256)
void knn_merge_kernel(const uint64_t* __restrict__ keysg, int* __restrict__ knn) {
    const int q = blockIdx.x * 256 + threadIdx.x;     // 0..B*N-1
    const uint64_t* A  = keysg + (size_t)q * 32;
    const uint64_t* Bp = A + 16;
    int pa = 0, pb = 0;
    uint64_t ha = A[0], hb = Bp[0];
    int* dst = knn + (size_t)q * K;
    #pragma unroll
    for (int k = 0; k < K; k++) {
        uint64_t mv = ha < hb ? ha : hb;
        dst[k] = (int)(mv & 0xFFFFFFFFu);
        if (mv == ha) { ++pa; ha = (pa < 16) ? A[pa] : ~0ull; }
        else          { ++pb; hb = (pb < 16) ? Bp[pb] : ~0ull; }
    }
}

// ---------------------------------------------------------------------------
// Kernel 2: MFMA MLP (round-15 proven): 2-term layer 1, 1-term bf16 layer 2,
// neighbor-gather prefetch pipeline, gelu_fast.
// ---------------------------------------------------------------------------
__device__ __forceinline__ float gelu_fast(float x) {
    float az = fabsf(x) * 0.70710678118654752440f;
    float t  = __builtin_amdgcn_rcpf(fmaf(0.3275911f, az, 1.0f));
    float p  = t * fmaf(t, fmaf(t, fmaf(t, fmaf(t, 1.061405429f, -1.453152027f),
                                        1.421413741f), -0.284496736f), 0.254829592f);
    float e  = p * __builtin_amdgcn_exp2f(-az * az * 1.44269504088896f); // 1-erf(az)
    float g  = 0.5f * x;
    return (x >= 0.0f) ? g * (2.0f - e) : g * e;
}

#define QPW 4

__global__ __launch_bounds__(256)
void mlp_mfma_kernel(const float* __restrict__ F,
                     const unsigned short* __restrict__ HP,
                     const unsigned short* __restrict__ MP,
                     const int* __restrict__ knn,
                     const float* __restrict__ W1, const float* __restrict__ b1,
                     const float* __restrict__ W2, const float* __restrict__ b2,
                     float* __restrict__ out) {
    __shared__ __align__(16) unsigned short W1h[64 * 128];   // 16KB
    __shared__ __align__(16) unsigned short W1m[64 * 128];   // 16KB
    __shared__ __align__(16) unsigned short hbh[4][1024];    // per-wave h hi (8KB)

    const int tid = threadIdx.x;
    const int l   = tid & 63;
    const int w   = tid >> 6;

    const int cb    = (l >> 4) * 8;
    const int swzL  = (l & 15) << 4;
    const int qbase = (blockIdx.x * 4 + w) * QPW;
    char* hbh_w = (char*)&hbh[w][0];

    // all knn indices for this wave's 4 queries, issued immediately
    int nbs[QPW];
    #pragma unroll
    for (int jq = 0; jq < QPW; jq++)
        nbs[jq] = knn[(size_t)(qbase + jq) * K + (l & 15)];

    for (int e = tid; e < 8192; e += 256) {   // W1 image: [n][k], swizzled, 2-term
        const int n = e & 63, k = e >> 6;
        const int srcrow = (k < 64) ? (64 + k) : (k - 64);
        float x = W1[srcrow * 64 + n];
        unsigned short hh = f2bf(x);
        unsigned short mm = f2bf(x - bf2f(hh));
        const int byte = (n * 256 + k * 2) ^ ((n & 15) << 4);
        *(unsigned short*)((char*)W1h + byte) = hh;
        *(unsigned short*)((char*)W1m + byte) = mm;
    }

    // W2 fragments in registers: hi only (1-term layer 2)
    short8 B2h[4][2];
    float b1v[4], b2v[4];
    {
        const int n = (l & 15);
        #pragma unroll
        for (int nt = 0; nt < 4; nt++) {
            const int nn = nt * 16 + n;
            b1v[nt] = b1[nn];
            b2v[nt] = b2[nn];
            #pragma unroll
            for (int c = 0; c < 2; c++) {
                const int k0 = c * 32 + (l >> 4) * 8;
                short8 vh;
                #pragma unroll
                for (int jj = 0; jj < 8; jj++)
                    vh[jj] = (short)f2bf(W2[(k0 + jj) * 64 + nn]);
                B2h[nt][c] = vh;
            }
        }
    }
    __syncthreads();

    // neighbor-row prefetch double buffer
    float4 pnA0[2], pnA1[2], pnB0[2], pnB1[2];
#define LOADN(s_, jq_) { \
        const int q_ = qbase + (jq_); \
        const float* Fb_ = F + (size_t)(q_ >> 12) * N * C; \
        const size_t nr_ = (size_t)nbs[jq_] * C; \
        pnA0[s_] = *(const float4*)(Fb_ + nr_ + cb); \
        pnA1[s_] = *(const float4*)(Fb_ + nr_ + cb + 4); \
        pnB0[s_] = *(const float4*)(Fb_ + nr_ + 32 + cb); \
        pnB1[s_] = *(const float4*)(Fb_ + nr_ + 36 + cb); \
    }
    LOADN(0, 0);

    #pragma unroll
    for (int jq = 0; jq < QPW; jq++) {
        const int sbuf = jq & 1;
        if (jq + 1 < QPW) LOADN(sbuf ^ 1, jq + 1);

        const int q  = qbase + jq;
        const int b  = q >> 12;
        const int ci = q & (N - 1);
        const float*          Fb  = F  + (size_t)b * N * C;
        const unsigned short* HPb = HP + (size_t)b * N * C;
        const unsigned short* MPb = MP + (size_t)b * N * C;

        float4 cA0 = *(const float4*)(Fb + (size_t)ci * C + cb);
        float4 cA1 = *(const float4*)(Fb + (size_t)ci * C + cb + 4);
        float4 cB0 = *(const float4*)(Fb + (size_t)ci * C + 32 + cb);
        float4 cB1 = *(const float4*)(Fb + (size_t)ci * C + 36 + cb);
        float4 nA0 = pnA0[sbuf], nA1 = pnA1[sbuf];
        float4 nB0 = pnB0[sbuf], nB1 = pnB1[sbuf];

        short8 ach0 = *(const short8*)(HPb + (size_t)ci * C + cb);
        short8 ach1 = *(const short8*)(HPb + (size_t)ci * C + 32 + cb);
        short8 acm0 = *(const short8*)(MPb + (size_t)ci * C + cb);
        short8 acm1 = *(const short8*)(MPb + (size_t)ci * C + 32 + cb);

        short8 adh0, adm0, adh1, adm1;
        {
            float d0[8] = {nA0.x - cA0.x, nA0.y - cA0.y, nA0.z - cA0.z, nA0.w - cA0.w,
                           nA1.x - cA1.x, nA1.y - cA1.y, nA1.z - cA1.z, nA1.w - cA1.w};
            float d1[8] = {nB0.x - cB0.x, nB0.y - cB0.y, nB0.z - cB0.z, nB0.w - cB0.w,
                           nB1.x - cB1.x, nB1.y - cB1.y, nB1.z - cB1.z, nB1.w - cB1.w};
            #pragma unroll
            for (int jj = 0; jj < 8; jj++) {
                unsigned short h0 = f2bf(d0[jj]);
                adh0[jj] = (short)h0; adm0[jj] = (short)f2bf(d0[jj] - bf2f(h0));
                unsigned short h1 = f2bf(d1[jj]);
                adh1[jj] = (short)h1; adm1[jj] = (short)f2bf(d1[jj] - bf2f(h1));
            }
        }

        // ---- layer 1 (2-term) ----
        #pragma unroll
        for (int nt = 0; nt < 4; nt++) {
            const int rowb = (nt * 16 + (l & 15)) * 256 + (l >> 4) * 16;
            f32x4 a1 = {0.f, 0.f, 0.f, 0.f};
            f32x4 a2 = {0.f, 0.f, 0.f, 0.f};
            #pragma unroll
            for (int kc = 0; kc < 4; kc++) {
                const int byte = (rowb + kc * 64) ^ swzL;
                short8 Bh = *(const short8*)((char*)W1h + byte);
                short8 Bm = *(const short8*)((char*)W1m + byte);
                short8 Ah = (kc == 0) ? adh0 : (kc == 1) ? adh1 : (kc == 2) ? ach0 : ach1;
                short8 Am = (kc == 0) ? adm0 : (kc == 1) ? adm1 : (kc == 2) ? acm0 : acm1;
                a1 = __builtin_amdgcn_mfma_f32_16x16x32_bf16(Ah, Bh, a1, 0, 0, 0);
                a2 = __builtin_amdgcn_mfma_f32_16x16x32_bf16(Ah, Bm, a2, 0, 0, 0);
                a2 = __builtin_amdgcn_mfma_f32_16x16x32_bf16(Am, Bh, a2, 0, 0, 0);
            }
            // gelu + hi-only transpose-store
            #pragma unroll
            for (int r = 0; r < 4; r++) {
                const int row = (l >> 4) * 4 + r;
                const int col = nt * 16 + (l & 15);
                float hv = gelu_fast(a1[r] + a2[r] + b1v[nt]);
                const int byte = (row * 128 + col * 2) ^ ((row & 7) << 4);
                *(unsigned short*)(hbh_w + byte) = f2bf(hv);
            }
        }

        asm volatile("s_waitcnt lgkmcnt(0)" ::: "memory");
        __builtin_amdgcn_sched_barrier(0);

        // ---- layer 2 (1-term): A = h-hi rows, B = W2-hi register frags ----
        short8 Ah2[2];
        #pragma unroll
        for (int kc = 0; kc < 2; kc++) {
            const int byte = ((l & 15) * 128 + kc * 64 + (l >> 4) * 16) ^ (((l & 15) & 7) << 4);
            Ah2[kc] = *(const short8*)(hbh_w + byte);
        }
        #pragma unroll
        for (int nt = 0; nt < 4; nt++) {
            f32x4 a1 = {0.f, 0.f, 0.f, 0.f};
            #pragma unroll
            for (int kc = 0; kc < 2; kc++)
                a1 = __builtin_amdgcn_mfma_f32_16x16x32_bf16(Ah2[kc], B2h[nt][kc], a1, 0, 0, 0);
            float mx = -INFINITY;
            #pragma unroll
            for (int r = 0; r < 4; r++)
                mx = fmaxf(mx, gelu_fast(a1[r] + b2v[nt]));
            mx = fmaxf(mx, __shfl_xor(mx, 16));
            mx = fmaxf(mx, __shfl_xor(mx, 32));
            if (l < 16) out[(size_t)q * D + nt * 16 + l] = mx;
        }
    }
#undef LOADN
}

// ---------------------------------------------------------------------------
extern "C" void kernel_launch(void* const* d_in, const int* in_sizes, int n_in,
                              void* d_out, int out_size, void* d_ws, size_t ws_size,
                              hipStream_t stream) {
    const float* F  = (const float*)d_in[0];
    const float* W1 = (const float*)d_in[1];
    const float* b1 = (const float*)d_in[2];
    const float* W2 = (const float*)d_in[3];
    const float* b2 = (const float*)d_in[4];
    float* out = (float*)d_out;

    char* ws = (char*)d_ws;
    float*          sq   = (float*)ws;                             // 128 KB
    uint64_t*       keys = (uint64_t*)(ws + (128 << 10));          // 8 MB
    unsigned short* HP   = (unsigned short*)(ws + (8320 << 10));   // 4 MB
    unsigned short* MP   = (unsigned short*)(ws + (12416 << 10));  // 4 MB
    unsigned short* LP   = (unsigned short*)(ws + (16512 << 10));  // 4 MB
    int*            knn  = (int*)LP;   // LP dead after knn_mfma pass (mlp uses HP/MP only)

    prep_kernel<<<dim3(384), 256, 0, stream>>>(F, sq, HP, MP, LP);
    knn_mfma_kernel<<<dim3(N / 128, 2, B), 512, 0, stream>>>(HP, MP, LP, sq, keys);
    knn_merge_kernel<<<dim3(B * N / 256), 256, 0, stream>>>(keys, knn);
    mlp_mfma_kernel<<<dim3(B * N / (4 * QPW)), 256, 0, stream>>>(
        F, HP, MP, knn, W1, b1, W2, b2, out);
}

// Round 18
// 238.207 us; speedup vs baseline: 1.1201x; 1.0658x over previous
//
#include <hip/hip_runtime.h>
#include <math.h>
#include <stdint.h>

#define B 8
#define N 4096
#define C 64
#define D 64
#define K 16

typedef __attribute__((ext_vector_type(8))) short short8;
typedef __attribute__((ext_vector_type(4))) float f32x4;

// ---------------------------------------------------------------------------
// bf16 helpers
// ---------------------------------------------------------------------------
__device__ __forceinline__ unsigned short f2bf(float x) {
    unsigned u = __float_as_uint(x);
    unsigned r = (u + 0x7FFFu + ((u >> 16) & 1u)) >> 16;   // RNE
    return (unsigned short)r;
}
__device__ __forceinline__ float bf2f(unsigned short h) {
    return __uint_as_float(((unsigned)h) << 16);
}

// key = (d2bits<<32)|idx reinterpreted as double. d2 finite >=0 -> positive
// finite double -> IEEE ordering == integer ordering (exact tie-break kept).
// f64 fmin/fmax comparators measured FASTER than u64 cmp+cndmask (round 12).
__device__ __forceinline__ double pack_key(float d2, unsigned idx) {
    uint2 u; u.x = idx; u.y = __float_as_uint(d2);
    return __builtin_bit_cast(double, u);
}

// ---------------------------------------------------------------------------
// Kernel 0: block-specialized prep (round-17 proven, byte-identical).
// ---------------------------------------------------------------------------
__global__ __launch_bounds__(256)
void prep_kernel(const float* __restrict__ F, float* __restrict__ sq,
                 unsigned short* __restrict__ HP, unsigned short* __restrict__ MP,
                 unsigned short* __restrict__ LP) {
    if (blockIdx.x < 128) {
        const int row = blockIdx.x * 256 + threadIdx.x;
        const float4* src = (const float4*)(F + (size_t)row * C);
        float4 v[16];
        #pragma unroll
        for (int q = 0; q < 16; q++) v[q] = src[q];

        float r[8];
        #pragma unroll
        for (int j = 0; j < 8; j++) {
            float t = ((const float*)v)[j];
            r[j] = t * t;
        }
        #pragma unroll
        for (int m = 1; m < 8; m++) {
            #pragma unroll
            for (int j = 0; j < 8; j++) {
                float t = ((const float*)v)[8 * m + j];
                r[j] = fmaf(t, t, r[j]);
            }
        }
        sq[row] = ((r[0] + r[1]) + (r[2] + r[3])) + ((r[4] + r[5]) + (r[6] + r[7]));
    } else {
        const int hr   = (blockIdx.x - 128) * 256 + threadIdx.x;  // 0..65535
        const int row  = hr >> 1;
        const int half = hr & 1;
        const float4* src = (const float4*)(F + (size_t)row * C + half * 32);
        float4 v[8];
        #pragma unroll
        for (int q = 0; q < 8; q++) v[q] = src[q];

        uint4* dh = (uint4*)(HP + (size_t)row * C) + half * 4;
        uint4* dm = (uint4*)(MP + (size_t)row * C) + half * 4;
        uint4* dl = (uint4*)(LP + (size_t)row * C) + half * 4;
        #pragma unroll
        for (int c8 = 0; c8 < 4; c8++) {          // 8 values per chunk
            unsigned hq[4], mq[4], lq[4];
            #pragma unroll
            for (int e = 0; e < 4; e++) {
                float x0 = ((const float*)v)[c8 * 8 + 2 * e];
                float x1 = ((const float*)v)[c8 * 8 + 2 * e + 1];
                unsigned short h0 = f2bf(x0), h1 = f2bf(x1);
                float r10 = x0 - bf2f(h0), r11 = x1 - bf2f(h1);
                unsigned short m0 = f2bf(r10), m1 = f2bf(r11);
                float r20 = r10 - bf2f(m0), r21 = r11 - bf2f(m1);
                unsigned short l0 = f2bf(r20), l1 = f2bf(r21);
                hq[e] = (unsigned)h0 | ((unsigned)h1 << 16);
                mq[e] = (unsigned)m0 | ((unsigned)m1 << 16);
                lq[e] = (unsigned)l0 | ((unsigned)l1 << 16);
            }
            dh[c8] = make_uint4(hq[0], hq[1], hq[2], hq[3]);
            dm[c8] = make_uint4(mq[0], mq[1], mq[2], mq[3]);
            dl[c8] = make_uint4(lq[0], lq[1], lq[2], lq[3]);
        }
    }
}

// ---------------------------------------------------------------------------
// 4-way merge of sorted lists for one query -> 16 sorted keys to dst
// ---------------------------------------------------------------------------
__device__ __forceinline__ void merge4_store(const uint64_t* __restrict__ keys,
                                             int qloc, uint64_t* __restrict__ dst) {
    const uint64_t* K0 = keys + (qloc * 4 + 0) * 16;
    const uint64_t* K1 = keys + (qloc * 4 + 1) * 16;
    const uint64_t* K2 = keys + (qloc * 4 + 2) * 16;
    const uint64_t* K3 = keys + (qloc * 4 + 3) * 16;
    int p0 = 0, p1 = 0, p2 = 0, p3 = 0;
    uint64_t h0 = K0[0], h1 = K1[0], h2 = K2[0], h3 = K3[0];
    #pragma unroll
    for (int k = 0; k < K; k++) {
        uint64_t m01 = h0 < h1 ? h0 : h1;
        uint64_t m23 = h2 < h3 ? h2 : h3;
        uint64_t mv  = m01 < m23 ? m01 : m23;
        dst[k] = mv;
        if      (mv == h0) { ++p0; h0 = (p0 < 16) ? K0[p0] : ~0ull; }
        else if (mv == h1) { ++p1; h1 = (p1 < 16) ? K1[p1] : ~0ull; }
        else if (mv == h2) { ++p2; h2 = (p2 < 16) ? K2[p2] : ~0ull; }
        else               { ++p3; h3 = (p3 < 16) ? K3[p3] : ~0ull; }
    }
}

// ---------------------------------------------------------------------------
// Kernel 1: MFMA KNN (round-13/15/17 proven, byte-identical). 512 threads /
// 8 waves, 128 queries/block, split-K x2, Batcher-63 f64 fmin/fmax selection.
// ---------------------------------------------------------------------------
__global__ __launch_bounds__(512, 2)
void knn_mfma_kernel(const unsigned short* __restrict__ HP,
                     const unsigned short* __restrict__ MP,
                     const unsigned short* __restrict__ LP,
                     const float* __restrict__ sqg, uint64_t* __restrict__ keysg) {
    __shared__ __align__(16) char lds[49152];   // buf0 = [0,24K), buf1 = [24K,48K)

    const int s  = blockIdx.y;                  // candidate half
    const int b  = blockIdx.z;
    const int i0 = blockIdx.x * 128;            // first query of block
    const int c0 = s * 2048;
    const unsigned short* Hb = HP + (size_t)b * N * C;
    const unsigned short* Mb = MP + (size_t)b * N * C;
    const unsigned short* Lb = LP + (size_t)b * N * C;
    const float* sqb = sqg + (size_t)b * N;

    const int tid = threadIdx.x;
    const int l   = tid & 63;
    const int w   = tid >> 6;                   // 0..7

    const int lr  = tid >> 3;                   // row 0..63
    const int lq  = tid & 7;                    // 16B chunk 0..7
    const int wbyte = (lr * 128 + lq * 16) ^ ((lr & 7) << 4);

    const double KMAX = __builtin_bit_cast(double, 0x7FEFFFFFFFFFFFFFull);

    // prefetch first candidate tile of this half (hides under Q staging)
    uint4 ph, pm, pl;
    {
        const size_t rb = (size_t)(c0 + lr) * C + lq * 8;
        ph = *(const uint4*)(Hb + rb);
        pm = *(const uint4*)(Mb + rb);
        pl = *(const uint4*)(Lb + rb);
    }

    {   // stage ALL 128 Q rows across both buffers (48KB)
        const size_t r0 = (size_t)(i0 + lr) * C + lq * 8;
        const size_t r1 = (size_t)(i0 + 64 + lr) * C + lq * 8;
        uint4 qh0 = *(const uint4*)(Hb + r0), qh1 = *(const uint4*)(Hb + r1);
        uint4 qm0 = *(const uint4*)(Mb + r0), qm1 = *(const uint4*)(Mb + r1);
        uint4 ql0 = *(const uint4*)(Lb + r0), ql1 = *(const uint4*)(Lb + r1);
        *(uint4*)(lds +              wbyte) = qh0;
        *(uint4*)(lds +  8192      + wbyte) = qm0;
        *(uint4*)(lds + 16384      + wbyte) = ql0;
        *(uint4*)(lds + 24576      + wbyte) = qh1;
        *(uint4*)(lds + 24576+8192 + wbyte) = qm1;
        *(uint4*)(lds + 24576+16384+ wbyte) = ql1;
    }
    __syncthreads();

    // B fragments (query), register-resident for the whole scan
    const int koff = (l >> 4) * 16;
    const int swzR = (l & 7) << 4;
    const int qrow = w * 16 + (l & 15);         // 0..127
    const char* qbuf = lds + ((qrow >> 6) ? 24576 : 0);
    const int qr6 = qrow & 63;
    const int qb0 = (qr6 * 128 + koff) ^ swzR;
    const int qb1 = (qr6 * 128 + 64 + koff) ^ swzR;
    short8 bh0 = *(const short8*)(qbuf + qb0),         bh1 = *(const short8*)(qbuf + qb1);
    short8 bm0 = *(const short8*)(qbuf +  8192 + qb0), bm1 = *(const short8*)(qbuf +  8192 + qb1);
    short8 bl0 = *(const short8*)(qbuf + 16384 + qb0), bl1 = *(const short8*)(qbuf + 16384 + qb1);

    const float sqq   = sqb[i0 + qrow];
    const int   qglob = i0 + qrow;
    const int   crow0 = (l >> 4) * 4;
    const int   dtile = i0 + ((w >> 2) << 6);   // wave-uniform diagonal tile

    __syncthreads();          // all waves finished reading Q

    // stage first candidate tile into buf0
    *(uint4*)(lds +         wbyte) = ph;
    *(uint4*)(lds +  8192 + wbyte) = pm;
    *(uint4*)(lds + 16384 + wbyte) = pl;
    {   // prefetch second tile
        const size_t rb = (size_t)(c0 + 64 + lr) * C + lq * 8;
        ph = *(const uint4*)(Hb + rb);
        pm = *(const uint4*)(Mb + rb);
        pl = *(const uint4*)(Lb + rb);
    }
    __syncthreads();          // first tile visible

    double bd[16];
    #pragma unroll
    for (int k = 0; k < 16; k++) bd[k] = KMAX;

    for (int t = 0; t < 32; t++) {
        const int j0 = c0 + t * 64;
        char* bufA = lds + ((t & 1) ? 24576 : 0);      // compute tile t
        char* bufB = lds + ((t & 1) ? 0 : 24576);      // stage tile t+1

        if (t < 31) {
            *(uint4*)(bufB +         wbyte) = ph;
            *(uint4*)(bufB +  8192 + wbyte) = pm;
            *(uint4*)(bufB + 16384 + wbyte) = pl;
        }
        if (t < 30) {
            const size_t rb = (size_t)(j0 + 128 + lr) * C + lq * 8;
            ph = *(const uint4*)(Hb + rb);
            pm = *(const uint4*)(Mb + rb);
            pl = *(const uint4*)(Lb + rb);
        }

        float4 sqm0 = *(const float4*)(sqb + j0 +      crow0);
        float4 sqm1 = *(const float4*)(sqb + j0 + 16 + crow0);
        float4 sqm2 = *(const float4*)(sqb + j0 + 32 + crow0);
        float4 sqm3 = *(const float4*)(sqb + j0 + 48 + crow0);

        double nk[16];

        #pragma unroll
        for (int m = 0; m < 4; m++) {
            const int arow = m * 16 + (l & 15);
            const int ab0 = (arow * 128 + koff) ^ swzR;
            const int ab1 = (arow * 128 + 64 + koff) ^ swzR;
            short8 ah0 = *(const short8*)(bufA + ab0);
            short8 ah1 = *(const short8*)(bufA + ab1);
            short8 am0 = *(const short8*)(bufA + 8192 + ab0);
            short8 am1 = *(const short8*)(bufA + 8192 + ab1);
            short8 al0 = *(const short8*)(bufA + 16384 + ab0);
            short8 al1 = *(const short8*)(bufA + 16384 + ab1);

            f32x4 acc1 = {0.f, 0.f, 0.f, 0.f};
            acc1 = __builtin_amdgcn_mfma_f32_16x16x32_bf16(am0, bm0, acc1, 0, 0, 0);
            acc1 = __builtin_amdgcn_mfma_f32_16x16x32_bf16(am1, bm1, acc1, 0, 0, 0);
            acc1 = __builtin_amdgcn_mfma_f32_16x16x32_bf16(ah0, bl0, acc1, 0, 0, 0);
            acc1 = __builtin_amdgcn_mfma_f32_16x16x32_bf16(ah1, bl1, acc1, 0, 0, 0);
            acc1 = __builtin_amdgcn_mfma_f32_16x16x32_bf16(al0, bh0, acc1, 0, 0, 0);
            f32x4 acc2 = {0.f, 0.f, 0.f, 0.f};
            acc2 = __builtin_amdgcn_mfma_f32_16x16x32_bf16(al1, bh1, acc2, 0, 0, 0);
            acc2 = __builtin_amdgcn_mfma_f32_16x16x32_bf16(ah0, bm0, acc2, 0, 0, 0);
            acc2 = __builtin_amdgcn_mfma_f32_16x16x32_bf16(ah1, bm1, acc2, 0, 0, 0);
            acc2 = __builtin_amdgcn_mfma_f32_16x16x32_bf16(am0, bh0, acc2, 0, 0, 0);
            acc2 = __builtin_amdgcn_mfma_f32_16x16x32_bf16(am1, bh1, acc2, 0, 0, 0);
            f32x4 acch = {0.f, 0.f, 0.f, 0.f};
            acch = __builtin_amdgcn_mfma_f32_16x16x32_bf16(ah0, bh0, acch, 0, 0, 0);
            acch = __builtin_amdgcn_mfma_f32_16x16x32_bf16(ah1, bh1, acch, 0, 0, 0);

            float4 sqm = (m == 0) ? sqm0 : (m == 1) ? sqm1 : (m == 2) ? sqm2 : sqm3;
            #pragma unroll
            for (int r = 0; r < 4; r++) {
                float sqc = (r == 0) ? sqm.x : (r == 1) ? sqm.y : (r == 2) ? sqm.z : sqm.w;
                float gg = acch[r] + (acc1[r] + acc2[r]);
                float d2 = fmaf(-2.0f, gg, sqq + sqc);
                d2 = fmaxf(d2, 0.0f);
                nk[m * 4 + r] = pack_key(d2, (unsigned)(j0 + m * 16 + crow0 + r));
            }
        }

        // diagonal tile only: kill self-match (wave-uniform branch)
        if (j0 == dtile) {
            #pragma unroll
            for (int m = 0; m < 4; m++)
                #pragma unroll
                for (int r = 0; r < 4; r++)
                    if ((j0 + m * 16 + crow0 + r) == qglob) nk[m * 4 + r] = KMAX;
        }

        // ---- Batcher odd-even mergesort, n=16, DESCENDING (63 comparators,
        //      f64 fmin/fmax: 2 instr/CAS — measured fastest, round 11/12) ----
        #pragma unroll
        for (int p = 1; p < 16; p <<= 1) {
            #pragma unroll
            for (int kk = p; kk >= 1; kk >>= 1) {
                #pragma unroll
                for (int j = kk % p; j <= 16 - 1 - kk; j += 2 * kk) {
                    #pragma unroll
                    for (int i = 0; i <= ((kk - 1 < 16 - j - kk - 1) ? kk - 1 : 16 - j - kk - 1); i++) {
                        if ((i + j) / (2 * p) == (i + j + kk) / (2 * p)) {
                            double a = nk[i + j], c2 = nk[i + j + kk];
                            nk[i + j]      = fmax(a, c2);   // descending
                            nk[i + j + kk] = fmin(a, c2);
                        }
                    }
                }
            }
        }
        // ---- lowest-16 of (bd asc ++ nk desc): elementwise min ----
        #pragma unroll
        for (int i = 0; i < 16; i++) bd[i] = fmin(bd[i], nk[i]);
        // ---- bd bitonic -> ascending cleanup (strides 8,4,2,1) ----
        #pragma unroll
        for (int j = 8; j > 0; j >>= 1) {
            #pragma unroll
            for (int i = 0; i < 16; i++) {
                int ixj = i ^ j;
                if (ixj > i) {
                    double a = bd[i], c2 = bd[ixj];
                    bd[i]   = fmin(a, c2);
                    bd[ixj] = fmax(a, c2);
                }
            }
        }

        __syncthreads();       // tile t+1 staged & prior reads done
    }

    // ---- epilogue: two 64-query passes (32KB key scratch each) ----
    uint64_t* keys = (uint64_t*)lds;
    if (w < 4) {               // pass A: queries i0..i0+63
        const int qloc = w * 16 + (l & 15);
        const int base = (qloc * 4 + (l >> 4)) * 16;
        #pragma unroll
        for (int k = 0; k < 16; k++)
            keys[base + k] = __builtin_bit_cast(uint64_t, bd[k]);
    }
    __syncthreads();
    if (tid < 64)
        merge4_store(keys, tid, keysg + ((size_t)b * N + i0 + tid) * 32 + s * 16);
    __syncthreads();
    if (w >= 4) {              // pass B: queries i0+64..i0+127
        const int qloc = (w - 4) * 16 + (l & 15);
        const int base = (qloc * 4 + (l >> 4)) * 16;
        #pragma unroll
        for (int k = 0; k < 16; k++)
            keys[base + k] = __builtin_bit_cast(uint64_t, bd[k]);
    }
    __syncthreads();
    if (tid < 64)
        merge4_store(keys, tid, keysg + ((size_t)b * N + i0 + 64 + tid) * 32 + s * 16);
}

// ---------------------------------------------------------------------------
// Kernel 1b: final 2-way merge of the two halves, one thread per query
// ---------------------------------------------------------------------------
__global__ __launch_bounds__(256)
void knn_merge_kernel(const uint64_t* __restrict__ keysg, int* __restrict__ knn) {
    const int q = blockIdx.x * 256 + threadIdx.x;     // 0..B*N-1
    const uint64_t* A  = keysg + (size_t)q * 32;
    const uint64_t* Bp = A + 16;
    int pa = 0, pb = 0;
    uint64_t ha = A[0], hb = Bp[0];
    int* dst = knn + (size_t)q * K;
    #pragma unroll
    for (int k = 0; k < K; k++) {
        uint64_t mv = ha < hb ? ha : hb;
        dst[k] = (int)(mv & 0xFFFFFFFFu);
        if (mv == ha) { ++pa; ha = (pa < 16) ? A[pa] : ~0ull; }
        else          { ++pb; hb = (pb < 16) ? Bp[pb] : ~0ull; }
    }
}

// ---------------------------------------------------------------------------
// Kernel 2: MFMA MLP — 1-term bf16 layer 1 AND layer 2 (error budget ~6-9e-3
// vs 1.56e-2 threshold; RMS model validated round 15). LDS 24KB -> 6 blocks/CU
// (+50% TLP for the gather-latency chain). Neighbor prefetch kept.
// ---------------------------------------------------------------------------
__device__ __forceinline__ float gelu_fast(float x) {
    float az = fabsf(x) * 0.70710678118654752440f;
    float t  = __builtin_amdgcn_rcpf(fmaf(0.3275911f, az, 1.0f));
    float p  = t * fmaf(t, fmaf(t, fmaf(t, fmaf(t, 1.061405429f, -1.453152027f),
                                        1.421413741f), -0.284496736f), 0.254829592f);
    float e  = p * __builtin_amdgcn_exp2f(-az * az * 1.44269504088896f); // 1-erf(az)
    float g  = 0.5f * x;
    return (x >= 0.0f) ? g * (2.0f - e) : g * e;
}

#define QPW 4

__global__ __launch_bounds__(256)
void mlp_mfma_kernel(const float* __restrict__ F,
                     const unsigned short* __restrict__ HP,
                     const int* __restrict__ knn,
                     const float* __restrict__ W1, const float* __restrict__ b1,
                     const float* __restrict__ W2, const float* __restrict__ b2,
                     float* __restrict__ out) {
    __shared__ __align__(16) unsigned short W1h[64 * 128];   // 16KB (hi only)
    __shared__ __align__(16) unsigned short hbh[4][1024];    // per-wave h hi (8KB)

    const int tid = threadIdx.x;
    const int l   = tid & 63;
    const int w   = tid >> 6;

    const int cb    = (l >> 4) * 8;
    const int swzL  = (l & 15) << 4;
    const int qbase = (blockIdx.x * 4 + w) * QPW;
    char* hbh_w = (char*)&hbh[w][0];

    // all knn indices for this wave's 4 queries, issued immediately
    int nbs[QPW];
    #pragma unroll
    for (int jq = 0; jq < QPW; jq++)
        nbs[jq] = knn[(size_t)(qbase + jq) * K + (l & 15)];

    for (int e = tid; e < 8192; e += 256) {   // W1 image: [n][k], swizzled, hi-only
        const int n = e & 63, k = e >> 6;
        const int srcrow = (k < 64) ? (64 + k) : (k - 64);
        const int byte = (n * 256 + k * 2) ^ ((n & 15) << 4);
        *(unsigned short*)((char*)W1h + byte) = f2bf(W1[srcrow * 64 + n]);
    }

    // W2 fragments in registers: hi only (1-term layer 2)
    short8 B2h[4][2];
    float b1v[4], b2v[4];
    {
        const int n = (l & 15);
        #pragma unroll
        for (int nt = 0; nt < 4; nt++) {
            const int nn = nt * 16 + n;
            b1v[nt] = b1[nn];
            b2v[nt] = b2[nn];
            #pragma unroll
            for (int c = 0; c < 2; c++) {
                const int k0 = c * 32 + (l >> 4) * 8;
                short8 vh;
                #pragma unroll
                for (int jj = 0; jj < 8; jj++)
                    vh[jj] = (short)f2bf(W2[(k0 + jj) * 64 + nn]);
                B2h[nt][c] = vh;
            }
        }
    }
    __syncthreads();

    // neighbor-row prefetch double buffer
    float4 pnA0[2], pnA1[2], pnB0[2], pnB1[2];
#define LOADN(s_, jq_) { \
        const int q_ = qbase + (jq_); \
        const float* Fb_ = F + (size_t)(q_ >> 12) * N * C; \
        const size_t nr_ = (size_t)nbs[jq_] * C; \
        pnA0[s_] = *(const float4*)(Fb_ + nr_ + cb); \
        pnA1[s_] = *(const float4*)(Fb_ + nr_ + cb + 4); \
        pnB0[s_] = *(const float4*)(Fb_ + nr_ + 32 + cb); \
        pnB1[s_] = *(const float4*)(Fb_ + nr_ + 36 + cb); \
    }
    LOADN(0, 0);

    #pragma unroll
    for (int jq = 0; jq < QPW; jq++) {
        const int sbuf = jq & 1;
        if (jq + 1 < QPW) LOADN(sbuf ^ 1, jq + 1);

        const int q  = qbase + jq;
        const int b  = q >> 12;
        const int ci = q & (N - 1);
        const float*          Fb  = F  + (size_t)b * N * C;
        const unsigned short* HPb = HP + (size_t)b * N * C;

        float4 cA0 = *(const float4*)(Fb + (size_t)ci * C + cb);
        float4 cA1 = *(const float4*)(Fb + (size_t)ci * C + cb + 4);
        float4 cB0 = *(const float4*)(Fb + (size_t)ci * C + 32 + cb);
        float4 cB1 = *(const float4*)(Fb + (size_t)ci * C + 36 + cb);
        float4 nA0 = pnA0[sbuf], nA1 = pnA1[sbuf];
        float4 nB0 = pnB0[sbuf], nB1 = pnB1[sbuf];

        short8 ach0 = *(const short8*)(HPb + (size_t)ci * C + cb);
        short8 ach1 = *(const short8*)(HPb + (size_t)ci * C + 32 + cb);

        short8 adh0, adh1;
        {
            float d0[8] = {nA0.x - cA0.x, nA0.y - cA0.y, nA0.z - cA0.z, nA0.w - cA0.w,
                           nA1.x - cA1.x, nA1.y - cA1.y, nA1.z - cA1.z, nA1.w - cA1.w};
            float d1[8] = {nB0.x - cB0.x, nB0.y - cB0.y, nB0.z - cB0.z, nB0.w - cB0.w,
                           nB1.x - cB1.x, nB1.y - cB1.y, nB1.z - cB1.z, nB1.w - cB1.w};
            #pragma unroll
            for (int jj = 0; jj < 8; jj++) {
                adh0[jj] = (short)f2bf(d0[jj]);
                adh1[jj] = (short)f2bf(d1[jj]);
            }
        }

        // ---- layer 1 (1-term hi-only) ----
        #pragma unroll
        for (int nt = 0; nt < 4; nt++) {
            const int rowb = (nt * 16 + (l & 15)) * 256 + (l >> 4) * 16;
            f32x4 a1 = {0.f, 0.f, 0.f, 0.f};
            #pragma unroll
            for (int kc = 0; kc < 4; kc++) {
                const int byte = (rowb + kc * 64) ^ swzL;
                short8 Bh = *(const short8*)((char*)W1h + byte);
                short8 Ah = (kc == 0) ? adh0 : (kc == 1) ? adh1 : (kc == 2) ? ach0 : ach1;
                a1 = __builtin_amdgcn_mfma_f32_16x16x32_bf16(Ah, Bh, a1, 0, 0, 0);
            }
            // gelu + hi-only transpose-store
            #pragma unroll
            for (int r = 0; r < 4; r++) {
                const int row = (l >> 4) * 4 + r;
                const int col = nt * 16 + (l & 15);
                float hv = gelu_fast(a1[r] + b1v[nt]);
                const int byte = (row * 128 + col * 2) ^ ((row & 7) << 4);
                *(unsigned short*)(hbh_w + byte) = f2bf(hv);
            }
        }

        asm volatile("s_waitcnt lgkmcnt(0)" ::: "memory");
        __builtin_amdgcn_sched_barrier(0);

        // ---- layer 2 (1-term): A = h-hi rows, B = W2-hi register frags ----
        short8 Ah2[2];
        #pragma unroll
        for (int kc = 0; kc < 2; kc++) {
            const int byte = ((l & 15) * 128 + kc * 64 + (l >> 4) * 16) ^ (((l & 15) & 7) << 4);
            Ah2[kc] = *(const short8*)(hbh_w + byte);
        }
        #pragma unroll
        for (int nt = 0; nt < 4; nt++) {
            f32x4 a1 = {0.f, 0.f, 0.f, 0.f};
            #pragma unroll
            for (int kc = 0; kc < 2; kc++)
                a1 = __builtin_amdgcn_mfma_f32_16x16x32_bf16(Ah2[kc], B2h[nt][kc], a1, 0, 0, 0);
            float mx = -INFINITY;
            #pragma unroll
            for (int r = 0; r < 4; r++)
                mx = fmaxf(mx, gelu_fast(a1[r] + b2v[nt]));
            mx = fmaxf(mx, __shfl_xor(mx, 16));
            mx = fmaxf(mx, __shfl_xor(mx, 32));
            if (l < 16) out[(size_t)q * D + nt * 16 + l] = mx;
        }
    }
#undef LOADN
}

// ---------------------------------------------------------------------------
extern "C" void kernel_launch(void* const* d_in, const int* in_sizes, int n_in,
                              void* d_out, int out_size, void* d_ws, size_t ws_size,
                              hipStream_t stream) {
    const float* F  = (const float*)d_in[0];
    const float* W1 = (const float*)d_in[1];
    const float* b1 = (const float*)d_in[2];
    const float* W2 = (const float*)d_in[3];
    const float* b2 = (const float*)d_in[4];
    float* out = (float*)d_out;

    char* ws = (char*)d_ws;
    float*          sq   = (float*)ws;                             // 128 KB
    uint64_t*       keys = (uint64_t*)(ws + (128 << 10));          // 8 MB
    unsigned short* HP   = (unsigned short*)(ws + (8320 << 10));   // 4 MB
    unsigned short* MP   = (unsigned short*)(ws + (12416 << 10));  // 4 MB
    unsigned short* LP   = (unsigned short*)(ws + (16512 << 10));  // 4 MB
    int*            knn  = (int*)LP;   // LP dead after knn_mfma pass (mlp uses HP only)

    prep_kernel<<<dim3(384), 256, 0, stream>>>(F, sq, HP, MP, LP);
    knn_mfma_kernel<<<dim3(N / 128, 2, B), 512, 0, stream>>>(HP, MP, LP, sq, keys);
    knn_merge_kernel<<<dim3(B * N / 256), 256, 0, stream>>>(keys, knn);
    mlp_mfma_kernel<<<dim3(B * N / (4 * QPW)), 256, 0, stream>>>(
        F, HP, knn, W1, b1, W2, b2, out);
}